// Round 1
// baseline (558.896 us; speedup 1.0000x reference)
//
#include <hip/hip_runtime.h>
#include <hip/hip_fp16.h>

#define N    8192
#define FIN  256
#define FOUT 128
#define BM   64
#define BN   64
#define JSPLIT 4

typedef _Float16 half8 __attribute__((ext_vector_type(8)));
typedef _Float16 half4v __attribute__((ext_vector_type(4)));
typedef float floatx4 __attribute__((ext_vector_type(4)));

// ---------------------------------------------------------------------------
// Kernel A: H = fp16(inp@W), H2 = fp16(inp@W2), H3T = fp16((inp@W3)^T)
// grid (N/64, 3), block 256. fp32 inputs converted to fp16 at staging;
// fp32 MFMA accumulation.
// ---------------------------------------------------------------------------
__global__ __launch_bounds__(256, 2)
void gemm3_kernel(const float* __restrict__ inp,
                  const float* __restrict__ W0,
                  const float* __restrict__ W1,
                  const float* __restrict__ W2,
                  _Float16* __restrict__ H,
                  _Float16* __restrict__ H2,
                  _Float16* __restrict__ H3T)
{
    __shared__ _Float16 As[64][40];    // [row][k32 + 8 pad] -> 2-way bank ok
    __shared__ _Float16 Bs[128][40];   // [n][k32 + 8 pad]
    const int which = blockIdx.y;
    const float* Wp = which == 0 ? W0 : (which == 1 ? W1 : W2);
    const int r0 = blockIdx.x * 64;
    const int tid  = threadIdx.x;
    const int wave = tid >> 6;
    const int lane = tid & 63;
    const int lo16 = lane & 15;
    const int quad = lane >> 4;

    floatx4 acc[8];
#pragma unroll
    for (int i = 0; i < 8; i++) acc[i] = (floatx4){0.f, 0.f, 0.f, 0.f};

    for (int kc = 0; kc < FIN; kc += 32) {
        __syncthreads();
        // stage A tile 64x32 (fp32 -> fp16), float4 global reads
        for (int c = tid; c < 64 * 8; c += 256) {
            int r = c >> 3, k4 = (c & 7) * 4;
            float4 v = *(const float4*)&inp[(size_t)(r0 + r) * FIN + kc + k4];
            As[r][k4 + 0] = (_Float16)v.x;
            As[r][k4 + 1] = (_Float16)v.y;
            As[r][k4 + 2] = (_Float16)v.z;
            As[r][k4 + 3] = (_Float16)v.w;
        }
        // stage B^T tile: Bs[n][k] = W[kc+k][n]
        for (int c = tid; c < 32 * 32; c += 256) {
            int k = c >> 5, n4 = (c & 31) * 4;
            float4 v = *(const float4*)&Wp[(size_t)(kc + k) * FOUT + n4];
            Bs[n4 + 0][k] = (_Float16)v.x;
            Bs[n4 + 1][k] = (_Float16)v.y;
            Bs[n4 + 2][k] = (_Float16)v.z;
            Bs[n4 + 3][k] = (_Float16)v.w;
        }
        __syncthreads();
        half8 a = *(const half8*)&As[wave * 16 + lo16][quad * 8];
#pragma unroll
        for (int nt = 0; nt < 8; nt++) {
            half8 b = *(const half8*)&Bs[nt * 16 + lo16][quad * 8];
            acc[nt] = __builtin_amdgcn_mfma_f32_16x16x32_f16(a, b, acc[nt], 0, 0, 0);
        }
    }
    const int arow = wave * 16 + quad * 4;   // C layout: row = quad*4+reg, col = lo16
    if (which < 2) {
        _Float16* outp = which == 0 ? H : H2;
#pragma unroll
        for (int nt = 0; nt < 8; nt++)
#pragma unroll
            for (int r = 0; r < 4; r++)
                outp[(size_t)(r0 + arow + r) * FOUT + nt * 16 + lo16] = (_Float16)acc[nt][r];
    } else {
        // transposed store: 4 consecutive rows -> 8B packed store
#pragma unroll
        for (int nt = 0; nt < 8; nt++) {
            half4v v;
#pragma unroll
            for (int r = 0; r < 4; r++) v[r] = (_Float16)acc[nt][r];
            *(half4v*)&H3T[(size_t)(nt * 16 + lo16) * N + r0 + arow] = v;
        }
    }
}

// ---------------------------------------------------------------------------
// Kernel B: flash-style masked attention over j-slices with online softmax.
// grid (N/BM, JSPLIT), block 256 (4 waves, 16 Q-rows each).
// Writes unnormalized O partials + per-row (m, l).
// ---------------------------------------------------------------------------
__global__ __launch_bounds__(256, 2)
void attn_kernel(const _Float16* __restrict__ Hq,   // [N][128]
                 const _Float16* __restrict__ Hk,   // [N][128]
                 const _Float16* __restrict__ VT,   // [128][N]
                 const int* __restrict__ adj,       // [N][N]
                 float* __restrict__ Opart,         // [JSPLIT][N][128]
                 float* __restrict__ mpart,         // [JSPLIT][N]
                 float* __restrict__ lpart)         // [JSPLIT][N]
{
    __shared__ _Float16 Ks[BN][136];        // K rows [j][feat128 + 8 pad]
    __shared__ _Float16 Vs[FOUT][BN + 8];   // V^T [outcol][j + 8 pad]
    __shared__ _Float16 Ps[4][16][BN + 8];  // per-wave P [qrow][j]

    const int tid  = threadIdx.x;
    const int wave = tid >> 6;
    const int lane = tid & 63;
    const int lo16 = lane & 15;
    const int quad = lane >> 4;
    const int i0   = blockIdx.x * BM;
    const int js   = blockIdx.y;
    const int jbeg = js * (N / JSPLIT);

    // Q fragments (A-layout): row = lane&15, k = quad*8 + j; 4 k-chunks of 32
    half8 q[4];
#pragma unroll
    for (int kc = 0; kc < 4; kc++)
        q[kc] = *(const half8*)&Hq[(size_t)(i0 + wave * 16 + lo16) * FOUT + kc * 32 + quad * 8];

    floatx4 O[8];
#pragma unroll
    for (int i = 0; i < 8; i++) O[i] = (floatx4){0.f, 0.f, 0.f, 0.f};
    float m_r[4], l_r[4];
#pragma unroll
    for (int r = 0; r < 4; r++) { m_r[r] = -1e12f; l_r[r] = 0.f; }

    const int arow = i0 + wave * 16 + quad * 4;   // C-layout row base

    for (int it = 0; it < (N / JSPLIT) / BN; it++) {
        const int j0 = jbeg + it * BN;

        // adjacency loads, issued early (C-layout pattern, each dword read once)
        int am[4][4];
#pragma unroll
        for (int nt = 0; nt < 4; nt++)
#pragma unroll
            for (int r = 0; r < 4; r++)
                am[nt][r] = adj[(size_t)(arow + r) * N + j0 + nt * 16 + lo16];

        __syncthreads();   // prev iter's LDS reads done before overwrite
        // stage K tile: BN x 128 fp16
        for (int c = tid; c < BN * 16; c += 256) {
            int n = c >> 4, kk = (c & 15) * 8;
            *(half8*)&Ks[n][kk] = *(const half8*)&Hk[(size_t)(j0 + n) * FOUT + kk];
        }
        // stage V^T tile: 128 x BN fp16
        for (int c = tid; c < FOUT * (BN / 8); c += 256) {
            int n = c >> 3, kk = (c & 7) * 8;
            *(half8*)&Vs[n][kk] = *(const half8*)&VT[(size_t)n * N + j0 + kk];
        }
        __syncthreads();

        // S = Q K^T  (fp32 acc)
        floatx4 S[4];
#pragma unroll
        for (int nt = 0; nt < 4; nt++) {
            S[nt] = (floatx4){0.f, 0.f, 0.f, 0.f};
#pragma unroll
            for (int kc = 0; kc < 4; kc++) {
                half8 b = *(const half8*)&Ks[nt * 16 + lo16][kc * 32 + quad * 8];
                S[nt] = __builtin_amdgcn_mfma_f32_16x16x32_f16(q[kc], b, S[nt], 0, 0, 0);
            }
        }

        // LeakyReLU then mask (matches ref order)
        float sv[4][4];
#pragma unroll
        for (int nt = 0; nt < 4; nt++)
#pragma unroll
            for (int r = 0; r < 4; r++) {
                float e = S[nt][r];
                e = e > 0.f ? e : 0.2f * e;
                sv[nt][r] = am[nt][r] != 0 ? e : -1e12f;
            }

        // row max (16-lane butterfly within quad)
        float alpha[4];
#pragma unroll
        for (int r = 0; r < 4; r++) {
            float v = fmaxf(fmaxf(sv[0][r], sv[1][r]), fmaxf(sv[2][r], sv[3][r]));
#pragma unroll
            for (int d = 1; d < 16; d <<= 1)
                v = fmaxf(v, __shfl_xor(v, d));
            float mn = fmaxf(m_r[r], v);
            alpha[r] = __expf(m_r[r] - mn);
            m_r[r] = mn;
        }

        // P = exp(sv - m); accumulate row sums; stash P (fp16) to LDS
        float rs[4] = {0.f, 0.f, 0.f, 0.f};
#pragma unroll
        for (int nt = 0; nt < 4; nt++)
#pragma unroll
            for (int r = 0; r < 4; r++) {
                float p = __expf(sv[nt][r] - m_r[r]);
                rs[r] += p;
                Ps[wave][quad * 4 + r][nt * 16 + lo16] = (_Float16)p;
            }
#pragma unroll
        for (int r = 0; r < 4; r++) {
            float v = rs[r];
#pragma unroll
            for (int d = 1; d < 16; d <<= 1)
                v += __shfl_xor(v, d);
            l_r[r] = l_r[r] * alpha[r] + v;
#pragma unroll
            for (int nt = 0; nt < 8; nt++)
                O[nt][r] *= alpha[r];
        }
        __syncthreads();   // P visible (also orders wave-local write->read)

        // O += P V   (P in A-layout from LDS, V^T B-frags contiguous)
#pragma unroll
        for (int kc = 0; kc < BN / 32; kc++) {
            half8 pa = *(const half8*)&Ps[wave][lo16][kc * 32 + quad * 8];
#pragma unroll
            for (int nt = 0; nt < 8; nt++) {
                half8 b = *(const half8*)&Vs[nt * 16 + lo16][kc * 32 + quad * 8];
                O[nt] = __builtin_amdgcn_mfma_f32_16x16x32_f16(pa, b, O[nt], 0, 0, 0);
            }
        }
    }

    // epilogue: unnormalized O + (m, l) partials
#pragma unroll
    for (int nt = 0; nt < 8; nt++)
#pragma unroll
        for (int r = 0; r < 4; r++)
            Opart[((size_t)js * N + arow + r) * FOUT + nt * 16 + lo16] = O[nt][r];
    if (lo16 == 0) {
#pragma unroll
        for (int r = 0; r < 4; r++) {
            mpart[js * N + arow + r] = m_r[r];
            lpart[js * N + arow + r] = l_r[r];
        }
    }
}

// ---------------------------------------------------------------------------
// Kernel C: combine j-split partials, normalize, ELU, fp32 out.
// ---------------------------------------------------------------------------
__global__ __launch_bounds__(256)
void combine_kernel(const float* __restrict__ Opart,
                    const float* __restrict__ mpart,
                    const float* __restrict__ lpart,
                    float* __restrict__ out)
{
    int idx = blockIdx.x * 256 + threadIdx.x;   // over N*32 float4s
    int i = idx >> 5;
    int c = (idx & 31) << 2;
    float m[JSPLIT];
    float M = -3.0e38f;
#pragma unroll
    for (int s = 0; s < JSPLIT; s++) { m[s] = mpart[s * N + i]; M = fmaxf(M, m[s]); }
    float w[JSPLIT];
    float L = 0.f;
#pragma unroll
    for (int s = 0; s < JSPLIT; s++) { w[s] = __expf(m[s] - M); L += lpart[s * N + i] * w[s]; }
    float4 o = {0.f, 0.f, 0.f, 0.f};
#pragma unroll
    for (int s = 0; s < JSPLIT; s++) {
        float4 v = *(const float4*)&Opart[((size_t)s * N + i) * FOUT + c];
        o.x += w[s] * v.x; o.y += w[s] * v.y; o.z += w[s] * v.z; o.w += w[s] * v.w;
    }
    float inv = 1.f / L;
    float r0 = o.x * inv, r1 = o.y * inv, r2 = o.z * inv, r3 = o.w * inv;
    float4 res;
    res.x = r0 > 0.f ? r0 : __expf(r0) - 1.f;
    res.y = r1 > 0.f ? r1 : __expf(r1) - 1.f;
    res.z = r2 > 0.f ? r2 : __expf(r2) - 1.f;
    res.w = r3 > 0.f ? r3 : __expf(r3) - 1.f;
    *(float4*)&out[(size_t)i * FOUT + c] = res;
}

// ---------------------------------------------------------------------------
extern "C" void kernel_launch(void* const* d_in, const int* in_sizes, int n_in,
                              void* d_out, int out_size, void* d_ws, size_t ws_size,
                              hipStream_t stream) {
    const float* inp = (const float*)d_in[0];
    const int*   adj = (const int*)d_in[1];
    const float* W0  = (const float*)d_in[2];
    const float* W1  = (const float*)d_in[3];
    const float* W2  = (const float*)d_in[4];
    float* out = (float*)d_out;

    char* ws = (char*)d_ws;
    _Float16* H   = (_Float16*)(ws);                      // 2 MB
    _Float16* H2  = (_Float16*)(ws + (2u << 20));         // 2 MB
    _Float16* H3T = (_Float16*)(ws + (4u << 20));         // 2 MB, [128][N]
    float* Opart  = (float*)(ws + (6u << 20));            // 16 MB
    float* mpart  = (float*)(ws + (22u << 20));           // 128 KB
    float* lpart  = (float*)(ws + (22u << 20) + (size_t)JSPLIT * N * sizeof(float));

    gemm3_kernel<<<dim3(N / 64, 3), 256, 0, stream>>>(inp, W0, W1, W2, H, H2, H3T);
    attn_kernel<<<dim3(N / BM, JSPLIT), 256, 0, stream>>>(H, H2, H3T, adj, Opart, mpart, lpart);
    combine_kernel<<<(N * FOUT / 4) / 256, 256, 0, stream>>>(Opart, mpart, lpart, out);
}